// Round 2
// baseline (76979.968 us; speedup 1.0000x reference)
//
#include <hip/hip_runtime.h>
#include <math.h>

// ---------------------------------------------------------------------------
// TinyMyo 8ch/400tok quant transformer — fp32 correctness baseline v2.
// Workspace-compact: int8 code storage for qkv / mlp intermediates.
// B=256 C=8 T=1000 PATCH=20 D=192 SEQ=400 L=8 H=3 DH=64 HID=768 NCLS=7
// ---------------------------------------------------------------------------

typedef unsigned int u32;

constexpr int   NB    = 256;
constexpr int   NL    = 8;
constexpr long  ROWS  = (long)NB * 400;          // 102400

// ---- logical scale slots (each = 16 shadow u32 words) ----
constexpr int SLOT_X    = 0;
constexpr int SLOT_PW   = 1;
constexpr int SLOT_EMB  = 2;
constexpr int SLOT_CLF  = 3;
constexpr int SLOT_POOL = 4;
// per-layer base 16+i*16: +0 wqkv +1 wo +2 w1 +3 w2 +4 q +5 k +6 v
//  +7 scores +8 probmax +9 ctx +10 attnout +11 gelu +12 mlpout
constexpr int N_SLOT = 200;
constexpr int N_SLOT_WORDS = N_SLOT * 16;        // 3200

// ---- ws layout (float units) ----  total 59,654,336 floats = 238.6 MB
constexpr long OFF_GM   = 3200;                    // 307200
constexpr long OFF_GL   = OFF_GM + 307200;         // 307200
constexpr long OFF_POOL = OFF_GL + 307200;         // 49152
constexpr long OFF_PWQ  = OFF_POOL + 49152;        // 3840
constexpr long OFF_CLFQ = OFF_PWQ + 3840;          // 1344
constexpr long OFF_H    = OFF_CLFQ + 1344;         // 19660800
constexpr long OFF_X    = OFF_H + 19660800;        // 19660800
constexpr long OFF_U    = OFF_X + 19660800;        // 19660800 (78.6MB: int8 codes OR fp32[rows,192])

// ---------------------------------------------------------------------------
// device helpers
// ---------------------------------------------------------------------------
__device__ __forceinline__ float warpMax(float v) {
#pragma unroll
  for (int o = 32; o > 0; o >>= 1) v = fmaxf(v, __shfl_down(v, o));
  return v;
}

__device__ __forceinline__ float read_max16(const u32* sc, int slot) {
  const u32* p = sc + slot * 16;
  u32 m = 0;
#pragma unroll
  for (int i = 0; i < 16; ++i) m = max(m, p[i]);
  return __uint_as_float(m);
}

__device__ __forceinline__ float fqs(float x, float s) {
  return fminf(fmaxf(rintf(x / s), -128.0f), 127.0f) * s;
}

// ---------------------------------------------------------------------------
// small utility kernels
// ---------------------------------------------------------------------------
__global__ void k_zero(u32* p, int n) {
  int i = blockIdx.x * blockDim.x + threadIdx.x;
  if (i < n) p[i] = 0u;
}

__global__ __launch_bounds__(256) void k_absmax(const float4* __restrict__ x, long n4,
                                                u32* __restrict__ slot) {
  float m = 0.f;
  for (long i = (long)blockIdx.x * blockDim.x + threadIdx.x; i < n4;
       i += (long)gridDim.x * blockDim.x) {
    float4 v = x[i];
    m = fmaxf(m, fmaxf(fmaxf(fabsf(v.x), fabsf(v.y)), fmaxf(fabsf(v.z), fabsf(v.w))));
  }
  __shared__ float red[4];
  m = warpMax(m);
  int lane = threadIdx.x & 63, w = threadIdx.x >> 6;
  if (lane == 0) red[w] = m;
  __syncthreads();
  if (threadIdx.x == 0) {
    float r = fmaxf(fmaxf(red[0], red[1]), fmaxf(red[2], red[3]));
    atomicMax(slot + (blockIdx.x & 15), __float_as_uint(r));
  }
}

__global__ __launch_bounds__(256) void k_quant4(const float4* __restrict__ in,
                                                float4* __restrict__ out, long n4,
                                                const u32* __restrict__ sc, int slot) {
  float s = read_max16(sc, slot) / 127.0f + 1e-8f;
  for (long i = (long)blockIdx.x * blockDim.x + threadIdx.x; i < n4;
       i += (long)gridDim.x * blockDim.x) {
    float4 v = in[i];
    v.x = fqs(v.x, s); v.y = fqs(v.y, s); v.z = fqs(v.z, s); v.w = fqs(v.w, s);
    out[i] = v;
  }
}

__global__ __launch_bounds__(256) void k_resadd4(float4* __restrict__ h,
                                                 const float4* __restrict__ raw, long n4,
                                                 const u32* __restrict__ sc, int slot) {
  float s = read_max16(sc, slot) / 127.0f + 1e-8f;
  for (long i = (long)blockIdx.x * blockDim.x + threadIdx.x; i < n4;
       i += (long)gridDim.x * blockDim.x) {
    float4 r = raw[i];
    float4 v = h[i];
    v.x += fqs(r.x, s); v.y += fqs(r.y, s); v.z += fqs(r.z, s); v.w += fqs(r.w, s);
    h[i] = v;
  }
}

// ---------------------------------------------------------------------------
// patch embed: 8 rows/block, 192 threads
// ---------------------------------------------------------------------------
__global__ __launch_bounds__(192) void k_patch(const float* __restrict__ x,
                                               const float* __restrict__ pwq,
                                               const float* __restrict__ pb,
                                               const u32* __restrict__ sc,
                                               float* __restrict__ emb,
                                               u32* __restrict__ embSlot) {
  __shared__ float xq[8][20];
  __shared__ float red[3];
  const int tid = threadIdx.x;
  const long rowBase = (long)blockIdx.x * 8;
  const float sx = read_max16(sc, SLOT_X) / 127.0f + 1e-8f;
  if (tid < 160) {
    int r = tid / 20, k = tid % 20;
    xq[r][k] = fqs(x[(rowBase + r) * 20 + k], sx);
  }
  __syncthreads();
  float wreg[20];
#pragma unroll
  for (int k = 0; k < 20; ++k) wreg[k] = pwq[tid * 20 + k];
  const float bias = pb[tid];
  float m = 0.f;
  for (int r = 0; r < 8; ++r) {
    float acc = bias;
#pragma unroll
    for (int k = 0; k < 20; ++k) acc += xq[r][k] * wreg[k];
    emb[(rowBase + r) * 192 + tid] = acc;
    m = fmaxf(m, fabsf(acc));
  }
  m = warpMax(m);
  if ((tid & 63) == 0) red[tid >> 6] = m;
  __syncthreads();
  if (tid == 0)
    atomicMax(embSlot + (blockIdx.x & 15),
              __float_as_uint(fmaxf(fmaxf(red[0], red[1]), red[2])));
}

// ---------------------------------------------------------------------------
// LayerNorm: one wave per row, 4 rows/block
// ---------------------------------------------------------------------------
__global__ __launch_bounds__(256) void k_ln(const float* __restrict__ x,
                                            const float* __restrict__ g,
                                            const float* __restrict__ bta,
                                            float* __restrict__ y, int rows) {
  int w = threadIdx.x >> 6, lane = threadIdx.x & 63;
  long row = (long)blockIdx.x * 4 + w;
  if (row >= rows) return;
  const float* xr = x + row * 192;
  float v0 = xr[lane], v1 = xr[lane + 64], v2 = xr[lane + 128];
  float s = v0 + v1 + v2;
#pragma unroll
  for (int o = 32; o > 0; o >>= 1) s += __shfl_down(s, o);
  s = __shfl(s, 0);
  float mean = s / 192.0f;
  float d0 = v0 - mean, d1 = v1 - mean, d2 = v2 - mean;
  float q = d0 * d0 + d1 * d1 + d2 * d2;
#pragma unroll
  for (int o = 32; o > 0; o >>= 1) q += __shfl_down(q, o);
  q = __shfl(q, 0);
  float rs = 1.0f / sqrtf(q / 192.0f + 1e-5f);
  float* yr = y + row * 192;
  yr[lane]       = d0 * rs * g[lane]       + bta[lane];
  yr[lane + 64]  = d1 * rs * g[lane + 64]  + bta[lane + 64];
  yr[lane + 128] = d2 * rs * g[lane + 128] + bta[lane + 128];
}

// ---------------------------------------------------------------------------
// GEMM: C = op(A)·fq(B)^T + bias [,gelu]. 128x128 tile, 256 threads, 8x8/thr.
// AM: 0 = fp32 A, 1 = int8-code A (dequant with slotA scale)
// OM: 0 = fp32 store + absmax, 1 = absmax only, 2 = int8-code store (slotO scales)
// ---------------------------------------------------------------------------
template <int AM, bool GELU, int OM>
__global__ __launch_bounds__(256) void k_gemm(
    const float* __restrict__ A, const signed char* __restrict__ A8, int slotA,
    const float* __restrict__ B, int slotW, const float* __restrict__ bias,
    float* __restrict__ C, signed char* __restrict__ C8, int M, int N, int K,
    u32* sc, int slotO, int colsPerSlot) {
  __shared__ float As[16][132];
  __shared__ float Bs[16][132];
  __shared__ float red[4];

  const int tid = threadIdx.x;
  const int tx = tid & 15, ty = tid >> 4;
  const long rowBase = (long)blockIdx.y * 128;
  const int colBase = blockIdx.x * 128;

  const float sW = read_max16(sc, slotW) / 127.0f + 1e-8f;
  float sA = 1.0f;
  if (AM == 1) sA = read_max16(sc, slotA) / 127.0f + 1e-8f;

  float acc[2][2][4][4];
#pragma unroll
  for (int a = 0; a < 2; ++a)
#pragma unroll
    for (int b = 0; b < 2; ++b)
#pragma unroll
      for (int i = 0; i < 4; ++i)
#pragma unroll
        for (int j = 0; j < 4; ++j) acc[a][b][i][j] = 0.f;

  for (int k0 = 0; k0 < K; k0 += 16) {
#pragma unroll
    for (int it = 0; it < 2; ++it) {
      int fi = it * 256 + tid;
      int lm = fi >> 2, lk4 = (fi & 3) * 4;
      float a0, a1, a2, a3;
      if (AM == 0) {
        float4 av = *(const float4*)(A + (rowBase + lm) * K + k0 + lk4);
        a0 = av.x; a1 = av.y; a2 = av.z; a3 = av.w;
      } else {
        int wv = *(const int*)(A8 + (rowBase + lm) * K + k0 + lk4);
        a0 = sA * (float)(signed char)(wv);
        a1 = sA * (float)(signed char)(wv >> 8);
        a2 = sA * (float)(signed char)(wv >> 16);
        a3 = sA * (float)(signed char)(wv >> 24);
      }
      As[lk4 + 0][lm] = a0; As[lk4 + 1][lm] = a1;
      As[lk4 + 2][lm] = a2; As[lk4 + 3][lm] = a3;
      float b0 = 0.f, b1 = 0.f, b2 = 0.f, b3 = 0.f;
      if (colBase + lm < N) {
        float4 bv = *(const float4*)(B + (long)(colBase + lm) * K + k0 + lk4);
        b0 = fqs(bv.x, sW); b1 = fqs(bv.y, sW);
        b2 = fqs(bv.z, sW); b3 = fqs(bv.w, sW);
      }
      Bs[lk4 + 0][lm] = b0; Bs[lk4 + 1][lm] = b1;
      Bs[lk4 + 2][lm] = b2; Bs[lk4 + 3][lm] = b3;
    }
    __syncthreads();
#pragma unroll
    for (int kk = 0; kk < 16; ++kk) {
      float4 a0 = *(const float4*)&As[kk][ty * 4];
      float4 a1 = *(const float4*)&As[kk][64 + ty * 4];
      float4 b0 = *(const float4*)&Bs[kk][tx * 4];
      float4 b1 = *(const float4*)&Bs[kk][64 + tx * 4];
      float ar[2][4] = {{a0.x, a0.y, a0.z, a0.w}, {a1.x, a1.y, a1.z, a1.w}};
      float br[2][4] = {{b0.x, b0.y, b0.z, b0.w}, {b1.x, b1.y, b1.z, b1.w}};
#pragma unroll
      for (int i2 = 0; i2 < 2; ++i2)
#pragma unroll
        for (int i = 0; i < 4; ++i)
#pragma unroll
          for (int j2 = 0; j2 < 2; ++j2)
#pragma unroll
            for (int j = 0; j < 4; ++j)
              acc[i2][j2][i][j] += ar[i2][i] * br[j2][j];
    }
    __syncthreads();
  }

  const float inv_sqrt2 = 0.70710678118654752440f;
  float sO[2] = {1.f, 1.f};
  if (OM == 2) {
#pragma unroll
    for (int j2 = 0; j2 < 2; ++j2) {
      int g0 = colBase + j2 * 64;
      if (g0 < N) sO[j2] = read_max16(sc, slotO + g0 / colsPerSlot) / 127.0f + 1e-8f;
    }
  }

  float smax2[2] = {0.f, 0.f};
#pragma unroll
  for (int j2 = 0; j2 < 2; ++j2) {
    int gc0 = colBase + j2 * 64 + tx * 4;
    if ((colBase + j2 * 64) < N) {
      float bb0 = bias[gc0 + 0], bb1 = bias[gc0 + 1];
      float bb2 = bias[gc0 + 2], bb3 = bias[gc0 + 3];
#pragma unroll
      for (int i2 = 0; i2 < 2; ++i2) {
#pragma unroll
        for (int i = 0; i < 4; ++i) {
          long row = rowBase + i2 * 64 + ty * 4 + i;
          float o0 = acc[i2][j2][i][0] + bb0;
          float o1 = acc[i2][j2][i][1] + bb1;
          float o2 = acc[i2][j2][i][2] + bb2;
          float o3 = acc[i2][j2][i][3] + bb3;
          if (GELU) {
            o0 = 0.5f * o0 * (1.0f + erff(o0 * inv_sqrt2));
            o1 = 0.5f * o1 * (1.0f + erff(o1 * inv_sqrt2));
            o2 = 0.5f * o2 * (1.0f + erff(o2 * inv_sqrt2));
            o3 = 0.5f * o3 * (1.0f + erff(o3 * inv_sqrt2));
          }
          if (OM == 2) {
            float s = sO[j2];
            int c0 = (int)fminf(fmaxf(rintf(o0 / s), -128.f), 127.f);
            int c1 = (int)fminf(fmaxf(rintf(o1 / s), -128.f), 127.f);
            int c2 = (int)fminf(fmaxf(rintf(o2 / s), -128.f), 127.f);
            int c3 = (int)fminf(fmaxf(rintf(o3 / s), -128.f), 127.f);
            u32 pack = (u32)(c0 & 0xff) | ((u32)(c1 & 0xff) << 8) |
                       ((u32)(c2 & 0xff) << 16) | ((u32)(c3 & 0xff) << 24);
            *(u32*)(C8 + row * N + gc0) = pack;
          } else {
            if (OM == 0) {
              *(float4*)(C + row * N + gc0) = make_float4(o0, o1, o2, o3);
            }
            smax2[j2] = fmaxf(smax2[j2],
                              fmaxf(fmaxf(fabsf(o0), fabsf(o1)),
                                    fmaxf(fabsf(o2), fabsf(o3))));
          }
        }
      }
    }
  }
  if (OM != 2) {
#pragma unroll
    for (int j2 = 0; j2 < 2; ++j2) {
      float m = warpMax(smax2[j2]);
      int lane = tid & 63, w = tid >> 6;
      if (lane == 0) red[w] = m;
      __syncthreads();
      if (tid == 0 && (colBase + j2 * 64) < N) {
        int slot = slotO + (colBase + j2 * 64) / colsPerSlot;
        float r = fmaxf(fmaxf(red[0], red[1]), fmaxf(red[2], red[3]));
        atomicMax(sc + slot * 16 + ((blockIdx.x + blockIdx.y) & 15), __float_as_uint(r));
      }
      __syncthreads();
    }
  }
}

// ---------------------------------------------------------------------------
// Attention on int8 qkv codes, integer-exact accumulation. 3 recompute phases.
// Block = 32 q-rows of one (b,h), 256 threads.
// ---------------------------------------------------------------------------
__device__ __forceinline__ float4 dec4(int wv) {
  return make_float4((float)(signed char)(wv), (float)(signed char)(wv >> 8),
                     (float)(signed char)(wv >> 16), (float)(signed char)(wv >> 24));
}

template <int PHASE>
__global__ __launch_bounds__(256) void k_attn(const signed char* __restrict__ qkv8,
                                              float* __restrict__ ctx,
                                              float* __restrict__ gm,
                                              float* __restrict__ gl, u32* sc, int slotQ,
                                              int slotSc, int slotPr, int slotCtx) {
  __shared__ float qs[32][68];
  __shared__ float ks[128][68];
  __shared__ float ss[32][132];
  __shared__ float red[4];

  const int tile = blockIdx.x;
  const int bh = blockIdx.y;
  const int b = bh / 3, hh = bh % 3;
  const int r0 = tile * 32;
  const int tid = threadIdx.x;

  const signed char* qb = qkv8 + ((long)b * 400) * 576 + hh * 64;
  const signed char* kb = qb + 192;
  const signed char* vb = qb + 384;

  const float sQ = read_max16(sc, slotQ + 0) / 127.0f + 1e-8f;
  const float sK = read_max16(sc, slotQ + 1) / 127.0f + 1e-8f;
  const float sV = read_max16(sc, slotQ + 2) / 127.0f + 1e-8f;
  const float sSc = sQ * sK * 0.125f;   // score = sSc * (integer qk sum)

#pragma unroll
  for (int it = 0; it < 2; ++it) {
    int fi = tid * 2 + it;
    int lr = fi >> 4, d4 = (fi & 15) * 4;
    float4 v = make_float4(0.f, 0.f, 0.f, 0.f);
    if (r0 + lr < 400) v = dec4(*(const int*)(qb + (long)(r0 + lr) * 576 + d4));
    *(float4*)&qs[lr][d4] = v;
  }

  float sS = 0.f, sP = 0.f, sPV = 0.f;
  if (PHASE >= 1) sS = read_max16(sc, slotSc) / 127.0f + 1e-8f;
  if (PHASE == 2) {
    sP = read_max16(sc, slotPr) / 255.0f + 1e-8f;
    sPV = sP * sV;
  }

  const int rblk = tid >> 5;        // 0..7
  const int cblk = tid & 31;        // 0..31
  const int pr = tid >> 3;          // PV row 0..31
  const int pd = (tid & 7) * 8;     // PV cols

  float tm[4], tl[4], acc8[8], rowm[4], rowl[4];
  float vmax = 0.f;
  if (PHASE == 1) {
#pragma unroll
    for (int i = 0; i < 4; ++i) { tm[i] = -INFINITY; tl[i] = 0.f; }
  }
  if (PHASE == 2) {
#pragma unroll
    for (int u = 0; u < 8; ++u) acc8[u] = 0.f;
#pragma unroll
    for (int i = 0; i < 4; ++i) {
      int rr = r0 + rblk * 4 + i; if (rr > 399) rr = 399;
      rowm[i] = gm[(long)bh * 400 + rr];
      rowl[i] = gl[(long)bh * 400 + rr];
    }
  }

  for (int c0 = 0; c0 < 400; c0 += 128) {
    const int clen = min(128, 400 - c0);
    __syncthreads();
#pragma unroll
    for (int it = 0; it < 8; ++it) {
      int fi = it * 256 + tid;
      int lc = fi >> 4, d4 = (fi & 15) * 4;
      float4 v = make_float4(0.f, 0.f, 0.f, 0.f);
      if (lc < clen) v = dec4(*(const int*)(kb + (long)(c0 + lc) * 576 + d4));
      *(float4*)&ks[lc][d4] = v;
    }
    __syncthreads();

    float accS[4][4];
#pragma unroll
    for (int i = 0; i < 4; ++i)
#pragma unroll
      for (int j = 0; j < 4; ++j) accS[i][j] = 0.f;
#pragma unroll
    for (int d0 = 0; d0 < 64; d0 += 4) {
      float4 qa[4], kv[4];
#pragma unroll
      for (int i = 0; i < 4; ++i) qa[i] = *(const float4*)&qs[rblk * 4 + i][d0];
#pragma unroll
      for (int j = 0; j < 4; ++j) kv[j] = *(const float4*)&ks[cblk + 32 * j][d0];
#pragma unroll
      for (int i = 0; i < 4; ++i)
#pragma unroll
        for (int j = 0; j < 4; ++j)
          accS[i][j] += qa[i].x * kv[j].x + qa[i].y * kv[j].y +
                        qa[i].z * kv[j].z + qa[i].w * kv[j].w;
    }

    if (PHASE == 0) {
#pragma unroll
      for (int i = 0; i < 4; ++i) {
        if (r0 + rblk * 4 + i >= 400) continue;
#pragma unroll
        for (int j = 0; j < 4; ++j) {
          if (cblk + 32 * j >= clen) continue;
          vmax = fmaxf(vmax, fabsf(accS[i][j] * sSc));
        }
      }
    } else if (PHASE == 1) {
#pragma unroll
      for (int i = 0; i < 4; ++i) {
        float q0[4];
        float cm = -INFINITY;
#pragma unroll
        for (int j = 0; j < 4; ++j) {
          bool valid = (cblk + 32 * j) < clen;
          float qv = valid ? fqs(accS[i][j] * sSc, sS) : -INFINITY;
          q0[j] = qv;
          cm = fmaxf(cm, qv);
        }
        if (cm != -INFINITY) {
          float nm = fmaxf(tm[i], cm);
          float sum = 0.f;
#pragma unroll
          for (int j = 0; j < 4; ++j)
            if ((cblk + 32 * j) < clen) sum += expf(q0[j] - nm);
          tl[i] = tl[i] * expf(tm[i] - nm) + sum;
          tm[i] = nm;
        }
      }
    } else {
#pragma unroll
      for (int i = 0; i < 4; ++i) {
#pragma unroll
        for (int j = 0; j < 4; ++j) {
          int cl = cblk + 32 * j;
          float pu = 0.f;
          if (cl < clen) {
            float qv = fqs(accS[i][j] * sSc, sS);
            float p = expf(qv - rowm[i]) / rowl[i];
            pu = fminf(fmaxf(rintf(p / sP), 0.0f), 255.0f);   // prob CODE
          }
          ss[rblk * 4 + i][cl] = pu;
        }
      }
      __syncthreads();
#pragma unroll
      for (int it = 0; it < 8; ++it) {
        int fi = it * 256 + tid;
        int lc = fi >> 4, d4 = (fi & 15) * 4;
        float4 v = make_float4(0.f, 0.f, 0.f, 0.f);
        if (lc < clen) v = dec4(*(const int*)(vb + (long)(c0 + lc) * 576 + d4));
        *(float4*)&ks[lc][d4] = v;
      }
      __syncthreads();
      for (int t4 = 0; t4 < clen; t4 += 4) {
        float4 p4 = *(const float4*)&ss[pr][t4];
        float pv[4] = {p4.x, p4.y, p4.z, p4.w};
#pragma unroll
        for (int u = 0; u < 4; ++u) {
          float4 va = *(const float4*)&ks[t4 + u][pd];
          float4 vb2 = *(const float4*)&ks[t4 + u][pd + 4];
          acc8[0] += pv[u] * va.x; acc8[1] += pv[u] * va.y;
          acc8[2] += pv[u] * va.z; acc8[3] += pv[u] * va.w;
          acc8[4] += pv[u] * vb2.x; acc8[5] += pv[u] * vb2.y;
          acc8[6] += pv[u] * vb2.z; acc8[7] += pv[u] * vb2.w;
        }
      }
    }
  }

  if (PHASE == 0) {
    float m = warpMax(vmax);
    int lane = tid & 63, w = tid >> 6;
    if (lane == 0) red[w] = m;
    __syncthreads();
    if (tid == 0) {
      float r = fmaxf(fmaxf(red[0], red[1]), fmaxf(red[2], red[3]));
      atomicMax(sc + slotSc * 16 + ((blockIdx.x + blockIdx.y) & 15), __float_as_uint(r));
    }
  } else if (PHASE == 1) {
    __syncthreads();
#pragma unroll
    for (int i = 0; i < 4; ++i) {
      ss[rblk * 4 + i][cblk] = tm[i];
      ss[rblk * 4 + i][64 + cblk] = tl[i];
    }
    __syncthreads();
    if (tid < 64) {
      float cand = 0.f;
      if (tid < 32 && (r0 + tid) < 400) {
        float m = -INFINITY;
#pragma unroll
        for (int cb = 0; cb < 32; ++cb) m = fmaxf(m, ss[tid][cb]);
        float l = 0.f;
#pragma unroll
        for (int cb = 0; cb < 32; ++cb) {
          float pm = ss[tid][cb], pl = ss[tid][64 + cb];
          if (pl > 0.f) l += pl * expf(pm - m);
        }
        gm[(long)bh * 400 + r0 + tid] = m;
        gl[(long)bh * 400 + r0 + tid] = l;
        cand = 1.0f / l;
      }
      cand = warpMax(cand);
      if (tid == 0)
        atomicMax(sc + slotPr * 16 + ((blockIdx.x + blockIdx.y) & 15), __float_as_uint(cand));
    }
  } else {
    float cm = 0.f;
    if (r0 + pr < 400) {
      float* cp = ctx + ((long)(b * 400 + r0 + pr)) * 192 + hh * 64 + pd;
      float o[8];
#pragma unroll
      for (int u = 0; u < 8; ++u) { o[u] = acc8[u] * sPV; cm = fmaxf(cm, fabsf(o[u])); }
      *(float4*)cp = make_float4(o[0], o[1], o[2], o[3]);
      *(float4*)(cp + 4) = make_float4(o[4], o[5], o[6], o[7]);
    }
    float m = warpMax(cm);
    int lane = tid & 63, w = tid >> 6;
    if (lane == 0) red[w] = m;
    __syncthreads();
    if (tid == 0) {
      float r = fmaxf(fmaxf(red[0], red[1]), fmaxf(red[2], red[3]));
      atomicMax(sc + slotCtx * 16 + ((blockIdx.x + blockIdx.y) & 15), __float_as_uint(r));
    }
  }
}

// ---------------------------------------------------------------------------
// final pool + logits
// ---------------------------------------------------------------------------
__global__ __launch_bounds__(192) void k_pool(const float* __restrict__ xln,
                                              float* __restrict__ pooled,
                                              u32* __restrict__ slot) {
  int b = blockIdx.x, d = threadIdx.x;
  float sum = 0.f;
  for (int s = 0; s < 400; ++s) sum += xln[((long)b * 400 + s) * 192 + d];
  float v = sum / 400.0f;
  pooled[(long)b * 192 + d] = v;
  __shared__ float red[3];
  float m = warpMax(fabsf(v));
  if ((d & 63) == 0) red[d >> 6] = m;
  __syncthreads();
  if (d == 0)
    atomicMax(slot + (b & 15), __float_as_uint(fmaxf(fmaxf(red[0], red[1]), red[2])));
}

__global__ __launch_bounds__(64) void k_logits(const float* __restrict__ pooled,
                                               const float* __restrict__ clfq,
                                               const float* __restrict__ clfb,
                                               const u32* __restrict__ sc,
                                               float* __restrict__ out) {
  int c = blockIdx.x, b = blockIdx.y, lane = threadIdx.x;
  float sp = read_max16(sc, SLOT_POOL) / 127.0f + 1e-8f;
  float acc = 0.f;
#pragma unroll
  for (int j = 0; j < 3; ++j) {
    int d = lane + 64 * j;
    acc += fqs(pooled[(long)b * 192 + d], sp) * clfq[c * 192 + d];
  }
#pragma unroll
  for (int o = 32; o > 0; o >>= 1) acc += __shfl_down(acc, o);
  if (lane == 0) out[b * 7 + c] = acc + clfb[c];
}

// ---------------------------------------------------------------------------
// host
// ---------------------------------------------------------------------------
static inline int gsz(long n4, long cap) {
  long g = (n4 + 255) / 256;
  return (int)(g < cap ? g : cap);
}

extern "C" void kernel_launch(void* const* d_in, const int* in_sizes, int n_in,
                              void* d_out, int out_size, void* d_ws, size_t ws_size,
                              hipStream_t stream) {
  (void)in_sizes; (void)n_in; (void)out_size; (void)ws_size;

  const float* x     = (const float*)d_in[0];
  const float* pw    = (const float*)d_in[1];
  const float* pb    = (const float*)d_in[2];
  const float* ln1g  = (const float*)d_in[3];
  const float* ln1b  = (const float*)d_in[4];
  const float* wqkv  = (const float*)d_in[5];
  const float* bqkv  = (const float*)d_in[6];
  const float* wo    = (const float*)d_in[7];
  const float* bo    = (const float*)d_in[8];
  const float* ln2g  = (const float*)d_in[9];
  const float* ln2b  = (const float*)d_in[10];
  const float* w1    = (const float*)d_in[11];
  const float* b1    = (const float*)d_in[12];
  const float* w2    = (const float*)d_in[13];
  const float* b2    = (const float*)d_in[14];
  const float* lnfg  = (const float*)d_in[15];
  const float* lnfb  = (const float*)d_in[16];
  const float* clfw  = (const float*)d_in[17];
  const float* clfb  = (const float*)d_in[18];

  float* ws = (float*)d_ws;
  u32*   sc = (u32*)d_ws;
  float* GM   = ws + OFF_GM;
  float* GL   = ws + OFF_GL;
  float* POOL = ws + OFF_POOL;
  float* PWQ  = ws + OFF_PWQ;
  float* CLFQ = ws + OFF_CLFQ;
  float* H    = ws + OFF_H;
  float* X    = ws + OFF_X;
  float* Uf   = ws + OFF_U;                       // fp32 view [rows,192]
  signed char* U8 = (signed char*)(ws + OFF_U);   // int8-code view
  float* out = (float*)d_out;

  k_zero<<<(N_SLOT_WORDS + 255) / 256, 256, 0, stream>>>(sc, N_SLOT_WORDS);

  // ---- weight absmax (no quant buffers; GEMMs fq on load) ----
  auto amax = [&](const float* p, long n, int slot) {
    k_absmax<<<gsz(n / 4, 256), 256, 0, stream>>>((const float4*)p, n / 4, sc + slot * 16);
  };
  amax(pw, 3840, SLOT_PW);
  amax(clfw, 1344, SLOT_CLF);
  amax(x, 2048000, SLOT_X);
  for (int i = 0; i < NL; ++i) {
    int Lb = 16 + i * 16;
    amax(wqkv + (long)i * 110592, 110592, Lb + 0);
    amax(wo   + (long)i * 36864,  36864,  Lb + 1);
    amax(w1   + (long)i * 147456, 147456, Lb + 2);
    amax(w2   + (long)i * 147456, 147456, Lb + 3);
  }
  // pre-quantized small weights
  k_quant4<<<gsz(960, 256), 256, 0, stream>>>((const float4*)pw, (float4*)PWQ, 960, sc, SLOT_PW);
  k_quant4<<<gsz(336, 256), 256, 0, stream>>>((const float4*)clfw, (float4*)CLFQ, 336, sc, SLOT_CLF);

  // ---- patch embed ----
  k_patch<<<12800, 192, 0, stream>>>(x, PWQ, pb, sc, X, sc + SLOT_EMB * 16);
  k_quant4<<<2048, 256, 0, stream>>>((const float4*)X, (float4*)H, 19660800 / 4, sc, SLOT_EMB);

  for (int i = 0; i < NL; ++i) {
    int Lb = 16 + i * 16;
    // --- attention ---
    k_ln<<<(int)(ROWS / 4), 256, 0, stream>>>(H, ln1g + i * 192, ln1b + i * 192, X, (int)ROWS);
    {
      dim3 g(5, 800);
      // pass 0: absmax of q/k/v groups
      k_gemm<0, false, 1><<<g, 256, 0, stream>>>(
          X, nullptr, 0, wqkv + (long)i * 110592, Lb + 0, bqkv + i * 576,
          nullptr, nullptr, (int)ROWS, 576, 192, sc, Lb + 4, 192);
      // pass 1: store int8 codes
      k_gemm<0, false, 2><<<g, 256, 0, stream>>>(
          X, nullptr, 0, wqkv + (long)i * 110592, Lb + 0, bqkv + i * 576,
          nullptr, U8, (int)ROWS, 576, 192, sc, Lb + 4, 192);
    }
    {
      dim3 ga(13, 768);
      k_attn<0><<<ga, 256, 0, stream>>>(U8, X, GM, GL, sc, Lb + 4, Lb + 7, Lb + 8, Lb + 9);
      k_attn<1><<<ga, 256, 0, stream>>>(U8, X, GM, GL, sc, Lb + 4, Lb + 7, Lb + 8, Lb + 9);
      k_attn<2><<<ga, 256, 0, stream>>>(U8, X, GM, GL, sc, Lb + 4, Lb + 7, Lb + 8, Lb + 9);
    }
    k_quant4<<<2048, 256, 0, stream>>>((const float4*)X, (float4*)X, 19660800 / 4, sc, Lb + 9);
    {
      dim3 g(2, 800);
      k_gemm<0, false, 0><<<g, 256, 0, stream>>>(
          X, nullptr, 0, wo + (long)i * 36864, Lb + 1, bo + i * 192,
          Uf, nullptr, (int)ROWS, 192, 192, sc, Lb + 10, 192);
    }
    k_resadd4<<<2048, 256, 0, stream>>>((float4*)H, (const float4*)Uf, 19660800 / 4, sc, Lb + 10);
    // --- MLP ---
    k_ln<<<(int)(ROWS / 4), 256, 0, stream>>>(H, ln2g + i * 192, ln2b + i * 192, X, (int)ROWS);
    {
      dim3 g(6, 800);
      k_gemm<0, true, 1><<<g, 256, 0, stream>>>(
          X, nullptr, 0, w1 + (long)i * 147456, Lb + 2, b1 + i * 768,
          nullptr, nullptr, (int)ROWS, 768, 192, sc, Lb + 11, 768);
      k_gemm<0, true, 2><<<g, 256, 0, stream>>>(
          X, nullptr, 0, w1 + (long)i * 147456, Lb + 2, b1 + i * 768,
          nullptr, U8, (int)ROWS, 768, 192, sc, Lb + 11, 768);
    }
    {
      dim3 g(2, 800);
      k_gemm<1, false, 0><<<g, 256, 0, stream>>>(
          nullptr, U8, Lb + 11, w2 + (long)i * 147456, Lb + 3, b2 + i * 192,
          X, nullptr, (int)ROWS, 192, 768, sc, Lb + 12, 192);
    }
    k_resadd4<<<2048, 256, 0, stream>>>((float4*)H, (const float4*)X, 19660800 / 4, sc, Lb + 12);
  }

  // ---- final LN + pool + classifier ----
  k_ln<<<(int)(ROWS / 4), 256, 0, stream>>>(H, lnfg, lnfb, X, (int)ROWS);
  k_pool<<<256, 192, 0, stream>>>(X, POOL, sc + SLOT_POOL * 16);
  {
    dim3 g(7, 256);
    k_logits<<<g, 64, 0, stream>>>(POOL, CLFQ, clfb, sc, out);
  }
}

// Round 3
// 11710.572 us; speedup vs baseline: 6.5735x; 6.5735x over previous
//
#include <hip/hip_runtime.h>
#include <math.h>

// ---------------------------------------------------------------------------
// TinyMyo 8ch/400tok quant transformer — bf16-MFMA version.
// B=256 C=8 T=1000 PATCH=20 D=192 SEQ=400 L=8 H=3 DH=64 HID=768 NCLS=7
// All quantized tensors are exact integer grids -> bf16 codes are exact and
// MFMA fp32 accumulation of code dot-products is exact (sums < 2^24).
// ---------------------------------------------------------------------------

typedef unsigned int u32;
typedef unsigned short u16;
typedef __attribute__((ext_vector_type(8))) short short8;
typedef __attribute__((ext_vector_type(4))) float f32x4;

#define MFMA16(a, b, c) __builtin_amdgcn_mfma_f32_16x16x32_bf16((a), (b), (c), 0, 0, 0)

constexpr int NL = 8;
constexpr long ROWS = 102400;  // B*SEQ

// ---- scale slots (each 16 shadow u32 words) ----
constexpr int SLOT_X = 0, SLOT_PW = 1, SLOT_EMB = 2, SLOT_CLF = 3, SLOT_POOL = 4;
// per-layer base 16+i*16: +0 wqkv +1 wo +2 w1 +3 w2 +4 q +5 k +6 v
//  +7 scores +8 probmax +9 ctx +10 attnout +11 gelu +12 mlpout
constexpr int N_SLOT_WORDS = 200 * 16;

// ---- ws layout (float units), total 59,653,536 floats = 238.6 MB ----
constexpr long OFF_GM = 3200;
constexpr long OFF_GL = OFF_GM + 307200;
constexpr long OFF_POOL = OFF_GL + 307200;
constexpr long OFF_PWQ = OFF_POOL + 49152;
constexpr long OFF_CLFQ = OFF_PWQ + 3840;
constexpr long OFF_H = OFF_CLFQ + 1344;     // fp32 residual
constexpr long OFF_A = OFF_H + 19660800;    // hi/lo bf16 planes | ctx fp32 | gemm fp32 out
constexpr long OFF_U = OFF_A + 19660800;    // int8 codes: qkv(59MB) / ctx(19.7MB) / gelu(78.6MB)

// ---------------------------------------------------------------------------
// helpers
// ---------------------------------------------------------------------------
__device__ __forceinline__ float warpMax(float v) {
#pragma unroll
  for (int o = 32; o > 0; o >>= 1) v = fmaxf(v, __shfl_down(v, o));
  return v;
}

__device__ __forceinline__ float read_max16(const u32* sc, int slot) {
  const u32* p = sc + slot * 16;
  u32 m = 0;
#pragma unroll
  for (int i = 0; i < 16; ++i) m = max(m, p[i]);
  return __uint_as_float(m);
}

__device__ __forceinline__ float fqs(float x, float s) {
  return fminf(fmaxf(rintf(x / s), -128.0f), 127.0f) * s;
}

__device__ __forceinline__ float bf2f(u16 h) { return __uint_as_float(((u32)h) << 16); }
__device__ __forceinline__ u16 f2bf(float f) {  // RNE float->bf16
  u32 b = __float_as_uint(f);
  return (u16)((b + 0x7FFFu + ((b >> 16) & 1u)) >> 16);
}
// exact for integer-valued floats |v| <= 256
__device__ __forceinline__ short i2bf(float v) { return (short)(u16)(__float_as_uint(v) >> 16); }
// weight -> quant code (bf16 bits of the integer code)
__device__ __forceinline__ short qcode(float x, float s) {
  return i2bf(fminf(fmaxf(rintf(x / s), -128.f), 127.f));
}
// 8 int8 codes (two packed words) -> short8 of bf16 codes
__device__ __forceinline__ short8 dec8(int lo, int hi) {
  short8 o;
#pragma unroll
  for (int j = 0; j < 4; ++j) {
    o[j] = i2bf((float)((signed char)(lo >> (8 * j))));
    o[j + 4] = i2bf((float)((signed char)(hi >> (8 * j))));
  }
  return o;
}

// ---------------------------------------------------------------------------
// small utility kernels
// ---------------------------------------------------------------------------
__global__ void k_zero(u32* p, int n) {
  int i = blockIdx.x * blockDim.x + threadIdx.x;
  if (i < n) p[i] = 0u;
}

__global__ __launch_bounds__(256) void k_absmax(const float4* __restrict__ x, long n4,
                                                u32* __restrict__ slot) {
  float m = 0.f;
  for (long i = (long)blockIdx.x * blockDim.x + threadIdx.x; i < n4;
       i += (long)gridDim.x * blockDim.x) {
    float4 v = x[i];
    m = fmaxf(m, fmaxf(fmaxf(fabsf(v.x), fabsf(v.y)), fmaxf(fabsf(v.z), fabsf(v.w))));
  }
  __shared__ float red[4];
  m = warpMax(m);
  int lane = threadIdx.x & 63, w = threadIdx.x >> 6;
  if (lane == 0) red[w] = m;
  __syncthreads();
  if (threadIdx.x == 0) {
    float r = fmaxf(fmaxf(red[0], red[1]), fmaxf(red[2], red[3]));
    atomicMax(slot + (blockIdx.x & 15), __float_as_uint(r));
  }
}

__global__ __launch_bounds__(256) void k_quant4(const float4* __restrict__ in,
                                                float4* __restrict__ out, long n4,
                                                const u32* __restrict__ sc, int slot) {
  float s = read_max16(sc, slot) / 127.0f + 1e-8f;
  for (long i = (long)blockIdx.x * blockDim.x + threadIdx.x; i < n4;
       i += (long)gridDim.x * blockDim.x) {
    float4 v = in[i];
    v.x = fqs(v.x, s); v.y = fqs(v.y, s); v.z = fqs(v.z, s); v.w = fqs(v.w, s);
    out[i] = v;
  }
}

// fp32 -> int8 codes (packed u32)
__global__ __launch_bounds__(256) void k_quant_codes(const float4* __restrict__ in,
                                                     u32* __restrict__ out, long n4,
                                                     const u32* __restrict__ sc, int slot) {
  float s = read_max16(sc, slot) / 127.0f + 1e-8f;
  for (long i = (long)blockIdx.x * blockDim.x + threadIdx.x; i < n4;
       i += (long)gridDim.x * blockDim.x) {
    float4 v = in[i];
    int c0 = (int)fminf(fmaxf(rintf(v.x / s), -128.f), 127.f);
    int c1 = (int)fminf(fmaxf(rintf(v.y / s), -128.f), 127.f);
    int c2 = (int)fminf(fmaxf(rintf(v.z / s), -128.f), 127.f);
    int c3 = (int)fminf(fmaxf(rintf(v.w / s), -128.f), 127.f);
    out[i] = (u32)(c0 & 0xff) | ((u32)(c1 & 0xff) << 8) | ((u32)(c2 & 0xff) << 16) |
             ((u32)(c3 & 0xff) << 24);
  }
}

__global__ __launch_bounds__(256) void k_resadd4(float4* __restrict__ h,
                                                 const float4* __restrict__ raw, long n4,
                                                 const u32* __restrict__ sc, int slot) {
  float s = read_max16(sc, slot) / 127.0f + 1e-8f;
  for (long i = (long)blockIdx.x * blockDim.x + threadIdx.x; i < n4;
       i += (long)gridDim.x * blockDim.x) {
    float4 r = raw[i];
    float4 v = h[i];
    v.x += fqs(r.x, s); v.y += fqs(r.y, s); v.z += fqs(r.z, s); v.w += fqs(r.w, s);
    h[i] = v;
  }
}

// ---------------------------------------------------------------------------
// patch embed: 8 rows/block, 192 threads
// ---------------------------------------------------------------------------
__global__ __launch_bounds__(192) void k_patch(const float* __restrict__ x,
                                               const float* __restrict__ pwq,
                                               const float* __restrict__ pb,
                                               const u32* __restrict__ sc,
                                               float* __restrict__ emb,
                                               u32* __restrict__ embSlot) {
  __shared__ float xq[8][20];
  __shared__ float red[3];
  const int tid = threadIdx.x;
  const long rowBase = (long)blockIdx.x * 8;
  const float sx = read_max16(sc, SLOT_X) / 127.0f + 1e-8f;
  if (tid < 160) {
    int r = tid / 20, k = tid % 20;
    xq[r][k] = fqs(x[(rowBase + r) * 20 + k], sx);
  }
  __syncthreads();
  float wreg[20];
#pragma unroll
  for (int k = 0; k < 20; ++k) wreg[k] = pwq[tid * 20 + k];
  const float bias = pb[tid];
  float m = 0.f;
  for (int r = 0; r < 8; ++r) {
    float acc = bias;
#pragma unroll
    for (int k = 0; k < 20; ++k) acc += xq[r][k] * wreg[k];
    emb[(rowBase + r) * 192 + tid] = acc;
    m = fmaxf(m, fabsf(acc));
  }
  m = warpMax(m);
  if ((tid & 63) == 0) red[tid >> 6] = m;
  __syncthreads();
  if (tid == 0)
    atomicMax(embSlot + (blockIdx.x & 15),
              __float_as_uint(fmaxf(fmaxf(red[0], red[1]), red[2])));
}

// ---------------------------------------------------------------------------
// LayerNorm: one wave per row; HILO -> hi/lo bf16 planes, else fp32
// ---------------------------------------------------------------------------
template <bool HILO>
__global__ __launch_bounds__(256) void k_ln(const float* __restrict__ x,
                                            const float* __restrict__ g,
                                            const float* __restrict__ bta,
                                            float* __restrict__ y, u16* __restrict__ yh,
                                            u16* __restrict__ yl, int rows) {
  int w = threadIdx.x >> 6, lane = threadIdx.x & 63;
  long row = (long)blockIdx.x * 4 + w;
  if (row >= rows) return;
  const float* xr = x + row * 192;
  float v0 = xr[lane], v1 = xr[lane + 64], v2 = xr[lane + 128];
  float s = v0 + v1 + v2;
#pragma unroll
  for (int o = 32; o > 0; o >>= 1) s += __shfl_down(s, o);
  s = __shfl(s, 0);
  float mean = s / 192.0f;
  float d0 = v0 - mean, d1 = v1 - mean, d2 = v2 - mean;
  float q = d0 * d0 + d1 * d1 + d2 * d2;
#pragma unroll
  for (int o = 32; o > 0; o >>= 1) q += __shfl_down(q, o);
  q = __shfl(q, 0);
  float rs = 1.0f / sqrtf(q / 192.0f + 1e-5f);
  float o0 = d0 * rs * g[lane] + bta[lane];
  float o1 = d1 * rs * g[lane + 64] + bta[lane + 64];
  float o2 = d2 * rs * g[lane + 128] + bta[lane + 128];
  if (HILO) {
    long b = row * 192;
    u16 h0 = f2bf(o0), h1 = f2bf(o1), h2 = f2bf(o2);
    yh[b + lane] = h0;       yl[b + lane] = f2bf(o0 - bf2f(h0));
    yh[b + lane + 64] = h1;  yl[b + lane + 64] = f2bf(o1 - bf2f(h1));
    yh[b + lane + 128] = h2; yl[b + lane + 128] = f2bf(o2 - bf2f(h2));
  } else {
    float* yr = y + row * 192;
    yr[lane] = o0; yr[lane + 64] = o1; yr[lane + 128] = o2;
  }
}

// ---------------------------------------------------------------------------
// MFMA GEMM: C[M,N] = op(A)[M,K] · codes(W[N,K])^T * alpha + bias
// AMODE 0: A = hi/lo bf16 planes (fp32 split);  1: A = int8 codes (alpha*=sA)
// OM 0: fp32 store + absmax;  1: absmax only;  2: int8 code store
// 128x128? -> BM=128, BN=64, BK=32; 256 thr / 4 waves (2Mx2N), per wave 4x2 frags
// ---------------------------------------------------------------------------
template <int AMODE, bool GELU, int OM>
__global__ __launch_bounds__(256) void k_gemm(
    const u16* __restrict__ Ahi, const u16* __restrict__ Alo,
    const signed char* __restrict__ A8, int slotA, const float* __restrict__ W, int slotW,
    const float* __restrict__ bias, float* __restrict__ C, signed char* __restrict__ C8,
    int N, int K, u32* __restrict__ sc, int slotO, int colsPerSlot) {
  __shared__ u16 Ash[128 * 56];
  __shared__ u16 Asl[128 * 56];
  __shared__ u16 Bsh[64 * 56];
  __shared__ float red[4];
  const int tid = threadIdx.x;
  const long rowBase = (long)blockIdx.y * 128;
  const int colBase = blockIdx.x * 64;
  const float sW = read_max16(sc, slotW) / 127.0f + 1e-8f;
  float alpha = sW;
  if (AMODE == 1) alpha *= read_max16(sc, slotA) / 127.0f + 1e-8f;

  const int lane = tid & 63, wv = tid >> 6;
  const int wm = wv >> 1, wn = wv & 1;
  const int fr = lane & 15, fk = lane >> 4;

  f32x4 acc[4][2];
#pragma unroll
  for (int m = 0; m < 4; ++m)
#pragma unroll
    for (int n = 0; n < 2; ++n) acc[m][n] = (f32x4){0.f, 0.f, 0.f, 0.f};

  const int arow = tid >> 1, ac2 = tid & 1;
  const int bn = tid >> 2, bc = tid & 3;

  for (int k0 = 0; k0 < K; k0 += 32) {
    if (AMODE == 0) {
      const long g = (rowBase + arow) * (long)K + k0 + ac2 * 16;
      *(short8*)&Ash[arow * 56 + ac2 * 16] = *(const short8*)(Ahi + g);
      *(short8*)&Ash[arow * 56 + ac2 * 16 + 8] = *(const short8*)(Ahi + g + 8);
      *(short8*)&Asl[arow * 56 + ac2 * 16] = *(const short8*)(Alo + g);
      *(short8*)&Asl[arow * 56 + ac2 * 16 + 8] = *(const short8*)(Alo + g + 8);
    } else {
      int4 v = *(const int4*)(A8 + (rowBase + arow) * (long)K + k0 + ac2 * 16);
      *(short8*)&Ash[arow * 56 + ac2 * 16] = dec8(v.x, v.y);
      *(short8*)&Ash[arow * 56 + ac2 * 16 + 8] = dec8(v.z, v.w);
    }
    {
      const float* bs = W + (long)(colBase + bn) * K + k0 + bc * 8;
      float4 b0 = *(const float4*)bs;
      float4 b1 = *(const float4*)(bs + 4);
      short8 o;
      o[0] = qcode(b0.x, sW); o[1] = qcode(b0.y, sW);
      o[2] = qcode(b0.z, sW); o[3] = qcode(b0.w, sW);
      o[4] = qcode(b1.x, sW); o[5] = qcode(b1.y, sW);
      o[6] = qcode(b1.z, sW); o[7] = qcode(b1.w, sW);
      *(short8*)&Bsh[bn * 56 + bc * 8] = o;
    }
    __syncthreads();
    short8 bf0 = *(short8*)&Bsh[(wn * 32 + fr) * 56 + fk * 8];
    short8 bf1 = *(short8*)&Bsh[(wn * 32 + 16 + fr) * 56 + fk * 8];
#pragma unroll
    for (int m = 0; m < 4; ++m) {
      short8 ah = *(short8*)&Ash[(wm * 64 + m * 16 + fr) * 56 + fk * 8];
      acc[m][0] = MFMA16(ah, bf0, acc[m][0]);
      acc[m][1] = MFMA16(ah, bf1, acc[m][1]);
      if (AMODE == 0) {
        short8 al = *(short8*)&Asl[(wm * 64 + m * 16 + fr) * 56 + fk * 8];
        acc[m][0] = MFMA16(al, bf0, acc[m][0]);
        acc[m][1] = MFMA16(al, bf1, acc[m][1]);
      }
    }
    __syncthreads();
  }

  float sO = 1.f;
  if (OM == 2) sO = read_max16(sc, slotO + colBase / colsPerSlot) / 127.0f + 1e-8f;
  const float inv_sqrt2 = 0.70710678118654752440f;
  float vmax = 0.f;
#pragma unroll
  for (int n = 0; n < 2; ++n) {
    const int col = colBase + wn * 32 + n * 16 + fr;
    const float bb = bias[col];
#pragma unroll
    for (int m = 0; m < 4; ++m) {
#pragma unroll
      for (int r = 0; r < 4; ++r) {
        const long row = rowBase + wm * 64 + m * 16 + fk * 4 + r;
        float val = acc[m][n][r] * alpha + bb;
        if (GELU) val = 0.5f * val * (1.0f + erff(val * inv_sqrt2));
        if (OM == 2) {
          float code = fminf(fmaxf(rintf(val / sO), -128.f), 127.f);
          C8[row * N + col] = (signed char)code;
        } else {
          if (OM == 0) C[row * N + col] = val;
          vmax = fmaxf(vmax, fabsf(val));
        }
      }
    }
  }
  if (OM != 2) {
    float m = warpMax(vmax);
    if ((tid & 63) == 0) red[tid >> 6] = m;
    __syncthreads();
    if (tid == 0) {
      float r = fmaxf(fmaxf(red[0], red[1]), fmaxf(red[2], red[3]));
      atomicMax(sc + (slotO + colBase / colsPerSlot) * 16 + ((blockIdx.x + blockIdx.y) & 15),
                __float_as_uint(r));
    }
  }
}

// ---------------------------------------------------------------------------
// Attention (MFMA). Block = 64 q-rows of one (b,h), 256 thr / 4 waves.
// Wave w owns q rows [16w,16w+16). Scores = integer QK dot * sSc (exact,
// bit-identical across phases). Keys processed in 128-wide chunks.
// ---------------------------------------------------------------------------
template <int PHASE>  // 0: score absmax; 1: row stats + max prob
__global__ __launch_bounds__(256) void k_attn_s(const signed char* __restrict__ qkv8,
                                                float* __restrict__ gm, float* __restrict__ gl,
                                                u32* __restrict__ sc, int slotQ, int slotSc,
                                                int slotPr) {
  __shared__ u16 Qs[64 * 72];
  __shared__ u16 Ks[128 * 72];
  __shared__ float red[4];
  const int tid = threadIdx.x;
  const int r0 = blockIdx.x * 64;
  const int bh = blockIdx.y, b = bh / 3, hh = bh % 3;
  const signed char* qb = qkv8 + (long)b * 400 * 576 + hh * 64;
  const signed char* kb = qb + 192;
  const float sQ = read_max16(sc, slotQ) / 127.0f + 1e-8f;
  const float sK = read_max16(sc, slotQ + 1) / 127.0f + 1e-8f;
  const float sSc = sQ * sK * 0.125f;
  const float sS = (PHASE == 1) ? (read_max16(sc, slotSc) / 127.0f + 1e-8f) : 0.f;

  {  // stage Q (zero-padded past row 400)
    int row = tid >> 2, c = tid & 3;
    int4 v = make_int4(0, 0, 0, 0);
    if (r0 + row < 400) v = *(const int4*)(qb + (long)(r0 + row) * 576 + c * 16);
    *(short8*)&Qs[row * 72 + c * 16] = dec8(v.x, v.y);
    *(short8*)&Qs[row * 72 + c * 16 + 8] = dec8(v.z, v.w);
  }
  const int lane = tid & 63, w = tid >> 6, fr = lane & 15, fk = lane >> 4;
  __syncthreads();
  short8 qf0 = *(short8*)&Qs[(16 * w + fr) * 72 + fk * 8];
  short8 qf1 = *(short8*)&Qs[(16 * w + fr) * 72 + 32 + fk * 8];

  float vmax = 0.f, tm[4], tl[4];
#pragma unroll
  for (int r = 0; r < 4; ++r) { tm[r] = -INFINITY; tl[r] = 0.f; }

  for (int c0 = 0; c0 < 400; c0 += 128) {
    __syncthreads();
    {  // stage K chunk
      int trow = tid >> 1, half = tid & 1;
      int4 v0 = make_int4(0, 0, 0, 0), v1 = v0;
      if (c0 + trow < 400) {
        v0 = *(const int4*)(kb + (long)(c0 + trow) * 576 + half * 32);
        v1 = *(const int4*)(kb + (long)(c0 + trow) * 576 + half * 32 + 16);
      }
      *(short8*)&Ks[trow * 72 + half * 32] = dec8(v0.x, v0.y);
      *(short8*)&Ks[trow * 72 + half * 32 + 8] = dec8(v0.z, v0.w);
      *(short8*)&Ks[trow * 72 + half * 32 + 16] = dec8(v1.x, v1.y);
      *(short8*)&Ks[trow * 72 + half * 32 + 24] = dec8(v1.z, v1.w);
    }
    __syncthreads();
#pragma unroll
    for (int tf = 0; tf < 8; ++tf) {
      short8 kf0 = *(short8*)&Ks[(tf * 16 + fr) * 72 + fk * 8];
      short8 kf1 = *(short8*)&Ks[(tf * 16 + fr) * 72 + 32 + fk * 8];
      f32x4 s = (f32x4){0.f, 0.f, 0.f, 0.f};
      s = MFMA16(qf0, kf0, s);
      s = MFMA16(qf1, kf1, s);
      const int t = c0 + tf * 16 + fr;
#pragma unroll
      for (int r = 0; r < 4; ++r) {
        const int q = r0 + 16 * w + fk * 4 + r;
        if (q < 400 && t < 400) {
          if (PHASE == 0) {
            vmax = fmaxf(vmax, fabsf(s[r] * sSc));
          } else {
            float qv = fqs(s[r] * sSc, sS);
            float nm = fmaxf(tm[r], qv);
            tl[r] = tl[r] * expf(tm[r] - nm) + expf(qv - nm);
            tm[r] = nm;
          }
        }
      }
    }
  }

  if (PHASE == 0) {
    float m = warpMax(vmax);
    if (lane == 0) red[w] = m;
    __syncthreads();
    if (tid == 0) {
      float r = fmaxf(fmaxf(red[0], red[1]), fmaxf(red[2], red[3]));
      atomicMax(sc + slotSc * 16 + ((blockIdx.x + blockIdx.y) & 15), __float_as_uint(r));
    }
  } else {
    // merge (m,l) across the 16 lanes sharing each q row
#pragma unroll
    for (int off = 1; off < 16; off <<= 1) {
#pragma unroll
      for (int r = 0; r < 4; ++r) {
        float om = __shfl_xor(tm[r], off);
        float ol = __shfl_xor(tl[r], off);
        float nm = fmaxf(tm[r], om);
        if (nm == -INFINITY) {
          tl[r] = 0.f;
        } else {
          tl[r] = tl[r] * expf(tm[r] - nm) + ol * expf(om - nm);
          tm[r] = nm;
        }
      }
    }
    float cand = 0.f;
    if (fr == 0) {
#pragma unroll
      for (int r = 0; r < 4; ++r) {
        int q = r0 + 16 * w + fk * 4 + r;
        if (q < 400) {
          gm[(long)bh * 400 + q] = tm[r];
          gl[(long)bh * 400 + q] = tl[r];
          cand = fmaxf(cand, 1.0f / tl[r]);
        }
      }
    }
    float m = warpMax(cand);
    if (lane == 0) red[w] = m;
    __syncthreads();
    if (tid == 0) {
      float r = fmaxf(fmaxf(red[0], red[1]), fmaxf(red[2], red[3]));
      atomicMax(sc + slotPr * 16 + ((blockIdx.x + blockIdx.y) & 15), __float_as_uint(r));
    }
  }
}

// PHASE 2: probs -> uint8 codes -> PV (out^T = Vt · P^T), ctx + absmax
__global__ __launch_bounds__(256) void k_attn_pv(const signed char* __restrict__ qkv8,
                                                 float* __restrict__ ctx,
                                                 const float* __restrict__ gm,
                                                 const float* __restrict__ gl,
                                                 u32* __restrict__ sc, int slotQ, int slotSc,
                                                 int slotPr, int slotCtx) {
  __shared__ u16 Qs[64 * 72];
  __shared__ u16 Ks[128 * 72];
  __shared__ u16 Ps[64 * 136];
  __shared__ u16 Vt[64 * 136];
  __shared__ float red[4];
  const int tid = threadIdx.x;
  const int r0 = blockIdx.x * 64;
  const int bh = blockIdx.y, b = bh / 3, hh = bh % 3;
  const signed char* qb = qkv8 + (long)b * 400 * 576 + hh * 64;
  const signed char* kb = qb + 192;
  const signed char* vb = qb + 384;
  const float sQ = read_max16(sc, slotQ) / 127.0f + 1e-8f;
  const float sK = read_max16(sc, slotQ + 1) / 127.0f + 1e-8f;
  const float sV = read_max16(sc, slotQ + 2) / 127.0f + 1e-8f;
  const float sSc = sQ * sK * 0.125f;
  const float sS = read_max16(sc, slotSc) / 127.0f + 1e-8f;
  const float sP = read_max16(sc, slotPr) / 255.0f + 1e-8f;
  const float sPV = sP * sV;

  {  // stage Q
    int row = tid >> 2, c = tid & 3;
    int4 v = make_int4(0, 0, 0, 0);
    if (r0 + row < 400) v = *(const int4*)(qb + (long)(r0 + row) * 576 + c * 16);
    *(short8*)&Qs[row * 72 + c * 16] = dec8(v.x, v.y);
    *(short8*)&Qs[row * 72 + c * 16 + 8] = dec8(v.z, v.w);
  }
  const int lane = tid & 63, w = tid >> 6, fr = lane & 15, fk = lane >> 4;
  __syncthreads();
  short8 qf0 = *(short8*)&Qs[(16 * w + fr) * 72 + fk * 8];
  short8 qf1 = *(short8*)&Qs[(16 * w + fr) * 72 + 32 + fk * 8];

  float rowm[4], rowl[4];
#pragma unroll
  for (int r = 0; r < 4; ++r) {
    int q = r0 + 16 * w + fk * 4 + r;
    if (q > 399) q = 399;
    rowm[r] = gm[(long)bh * 400 + q];
    rowl[r] = gl[(long)bh * 400 + q];
  }
  f32x4 accT[4];
#pragma unroll
  for (int qf = 0; qf < 4; ++qf) accT[qf] = (f32x4){0.f, 0.f, 0.f, 0.f};

  for (int c0 = 0; c0 < 400; c0 += 128) {
    __syncthreads();
    {  // stage K chunk + transposed V chunk
      int trow = tid >> 1, half = tid & 1;
      int4 v0 = make_int4(0, 0, 0, 0), v1 = v0, u0 = v0, u1 = v0;
      if (c0 + trow < 400) {
        const signed char* kr = kb + (long)(c0 + trow) * 576 + half * 32;
        v0 = *(const int4*)kr;
        v1 = *(const int4*)(kr + 16);
        const signed char* vr = vb + (long)(c0 + trow) * 576 + half * 32;
        u0 = *(const int4*)vr;
        u1 = *(const int4*)(vr + 16);
      }
      *(short8*)&Ks[trow * 72 + half * 32] = dec8(v0.x, v0.y);
      *(short8*)&Ks[trow * 72 + half * 32 + 8] = dec8(v0.z, v0.w);
      *(short8*)&Ks[trow * 72 + half * 32 + 16] = dec8(v1.x, v1.y);
      *(short8*)&Ks[trow * 72 + half * 32 + 24] = dec8(v1.z, v1.w);
      short8 s0 = dec8(u0.x, u0.y), s1 = dec8(u0.z, u0.w);
      short8 s2 = dec8(u1.x, u1.y), s3 = dec8(u1.z, u1.w);
#pragma unroll
      for (int j = 0; j < 8; ++j) {
        Vt[(half * 32 + j) * 136 + trow] = (u16)s0[j];
        Vt[(half * 32 + 8 + j) * 136 + trow] = (u16)s1[j];
        Vt[(half * 32 + 16 + j) * 136 + trow] = (u16)s2[j];
        Vt[(half * 32 + 24 + j) * 136 + trow] = (u16)s3[j];
      }
    }
    __syncthreads();
    // scores -> prob codes into Ps[q][t]
#pragma unroll
    for (int tf = 0; tf < 8; ++tf) {
      short8 kf0 = *(short8*)&Ks[(tf * 16 + fr) * 72 + fk * 8];
      short8 kf1 = *(short8*)&Ks[(tf * 16 + fr) * 72 + 32 + fk * 8];
      f32x4 s = (f32x4){0.f, 0.f, 0.f, 0.f};
      s = MFMA16(qf0, kf0, s);
      s = MFMA16(qf1, kf1, s);
      const int t = c0 + tf * 16 + fr;
#pragma unroll
      for (int r = 0; r < 4; ++r) {
        const int q = r0 + 16 * w + fk * 4 + r;
        float pu = 0.f;
        if (q < 400 && t < 400) {
          float qv = fqs(s[r] * sSc, sS);
          float p = expf(qv - rowm[r]) / rowl[r];
          pu = fminf(fmaxf(rintf(p / sP), 0.f), 255.f);
        }
        Ps[(16 * w + fk * 4 + r) * 136 + tf * 16 + fr] = (u16)i2bf(pu);
      }
    }
    __syncthreads();
    // PV: accT[qf] += Vt-frag · P^T-frag
    short8 vf0 = *(short8*)&Vt[(16 * w + fr) * 136 + 0 + fk * 8];
    short8 vf1 = *(short8*)&Vt[(16 * w + fr) * 136 + 32 + fk * 8];
    short8 vf2 = *(short8*)&Vt[(16 * w + fr) * 136 + 64 + fk * 8];
    short8 vf3 = *(short8*)&Vt[(16 * w + fr) * 136 + 96 + fk * 8];
#pragma unroll
    for (int qf = 0; qf < 4; ++qf) {
      short8 pf0 = *(short8*)&Ps[(qf * 16 + fr) * 136 + 0 + fk * 8];
      short8 pf1 = *(short8*)&Ps[(qf * 16 + fr) * 136 + 32 + fk * 8];
      short8 pf2 = *(short8*)&Ps[(qf * 16 + fr) * 136 + 64 + fk * 8];
      short8 pf3 = *(short8*)&Ps[(qf * 16 + fr) * 136 + 96 + fk * 8];
      accT[qf] = MFMA16(vf0, pf0, accT[qf]);
      accT[qf] = MFMA16(vf1, pf1, accT[qf]);
      accT[qf] = MFMA16(vf2, pf2, accT[qf]);
      accT[qf] = MFMA16(vf3, pf3, accT[qf]);
    }
  }
  // epilogue: ctx[(b*400+q)*192 + hh*64 + d], d = 16w + fk*4 + r (float4/lane)
  float vmax = 0.f;
#pragma unroll
  for (int qf = 0; qf < 4; ++qf) {
    const int q = r0 + qf * 16 + fr;
    if (q < 400) {
      float4 o;
      o.x = accT[qf][0] * sPV; o.y = accT[qf][1] * sPV;
      o.z = accT[qf][2] * sPV; o.w = accT[qf][3] * sPV;
      vmax = fmaxf(vmax, fmaxf(fmaxf(fabsf(o.x), fabsf(o.y)), fmaxf(fabsf(o.z), fabsf(o.w))));
      *(float4*)&ctx[(long)(b * 400 + q) * 192 + hh * 64 + 16 * w + fk * 4] = o;
    }
  }
  float m = warpMax(vmax);
  if (lane == 0) red[w] = m;
  __syncthreads();
  if (tid == 0) {
    float r = fmaxf(fmaxf(red[0], red[1]), fmaxf(red[2], red[3]));
    atomicMax(sc + slotCtx * 16 + ((blockIdx.x + blockIdx.y) & 15), __float_as_uint(r));
  }
}

// ---------------------------------------------------------------------------
// final pool + logits
// ---------------------------------------------------------------------------
__global__ __launch_bounds__(192) void k_pool(const float* __restrict__ xln,
                                              float* __restrict__ pooled,
                                              u32* __restrict__ slot) {
  int b = blockIdx.x, d = threadIdx.x;
  float sum = 0.f;
  for (int s = 0; s < 400; ++s) sum += xln[((long)b * 400 + s) * 192 + d];
  float v = sum / 400.0f;
  pooled[(long)b * 192 + d] = v;
  __shared__ float red[3];
  float m = warpMax(fabsf(v));
  if ((d & 63) == 0) red[d >> 6] = m;
  __syncthreads();
  if (d == 0)
    atomicMax(slot + (b & 15), __float_as_uint(fmaxf(fmaxf(red[0], red[1]), red[2])));
}

__global__ __launch_bounds__(64) void k_logits(const float* __restrict__ pooled,
                                               const float* __restrict__ clfq,
                                               const float* __restrict__ clfb,
                                               const u32* __restrict__ sc,
                                               float* __restrict__ out) {
  int c = blockIdx.x, b = blockIdx.y, lane = threadIdx.x;
  float sp = read_max16(sc, SLOT_POOL) / 127.0f + 1e-8f;
  float acc = 0.f;
#pragma unroll
  for (int j = 0; j < 3; ++j) {
    int d = lane + 64 * j;
    acc += fqs(pooled[(long)b * 192 + d], sp) * clfq[c * 192 + d];
  }
#pragma unroll
  for (int o = 32; o > 0; o >>= 1) acc += __shfl_down(acc, o);
  if (lane == 0) out[b * 7 + c] = acc + clfb[c];
}

// ---------------------------------------------------------------------------
// host
// ---------------------------------------------------------------------------
static inline int gsz(long n4, long cap) {
  long g = (n4 + 255) / 256;
  return (int)(g < cap ? g : cap);
}

extern "C" void kernel_launch(void* const* d_in, const int* in_sizes, int n_in,
                              void* d_out, int out_size, void* d_ws, size_t ws_size,
                              hipStream_t stream) {
  (void)in_sizes; (void)n_in; (void)out_size; (void)ws_size;

  const float* x = (const float*)d_in[0];
  const float* pw = (const float*)d_in[1];
  const float* pb = (const float*)d_in[2];
  const float* ln1g = (const float*)d_in[3];
  const float* ln1b = (const float*)d_in[4];
  const float* wqkv = (const float*)d_in[5];
  const float* bqkv = (const float*)d_in[6];
  const float* wo = (const float*)d_in[7];
  const float* bo = (const float*)d_in[8];
  const float* ln2g = (const float*)d_in[9];
  const float* ln2b = (const float*)d_in[10];
  const float* w1 = (const float*)d_in[11];
  const float* b1 = (const float*)d_in[12];
  const float* w2 = (const float*)d_in[13];
  const float* b2 = (const float*)d_in[14];
  const float* lnfg = (const float*)d_in[15];
  const float* lnfb = (const float*)d_in[16];
  const float* clfw = (const float*)d_in[17];
  const float* clfb = (const float*)d_in[18];

  float* ws = (float*)d_ws;
  u32* sc = (u32*)d_ws;
  float* GM = ws + OFF_GM;
  float* GL = ws + OFF_GL;
  float* POOL = ws + OFF_POOL;
  float* PWQ = ws + OFF_PWQ;
  float* CLFQ = ws + OFF_CLFQ;
  float* H = ws + OFF_H;
  float* Af = ws + OFF_A;                    // fp32 view
  u16* XH = (u16*)(ws + OFF_A);              // hi plane (bf16)
  u16* XL = XH + 19660800;                   // lo plane
  signed char* U8 = (signed char*)(ws + OFF_U);
  float* out = (float*)d_out;

  k_zero<<<(N_SLOT_WORDS + 255) / 256, 256, 0, stream>>>(sc, N_SLOT_WORDS);

  auto amax = [&](const float* p, long n, int slot) {
    k_absmax<<<gsz(n / 4, 256), 256, 0, stream>>>((const float4*)p, n / 4, sc + slot * 16);
  };
  amax(pw, 3840, SLOT_PW);
  amax(clfw, 1344, SLOT_CLF);
  amax(x, 2048000, SLOT_X);
  for (int i = 0; i < NL; ++i) {
    int Lb = 16 + i * 16;
    amax(wqkv + (long)i * 110592, 110592, Lb + 0);
    amax(wo + (long)i * 36864, 36864, Lb + 1);
    amax(w1 + (long)i * 147456, 147456, Lb + 2);
    amax(w2 + (long)i * 147456, 147456, Lb + 3);
  }
  k_quant4<<<gsz(960, 256), 256, 0, stream>>>((const float4*)pw, (float4*)PWQ, 960, sc, SLOT_PW);
  k_quant4<<<gsz(336, 256), 256, 0, stream>>>((const float4*)clfw, (float4*)CLFQ, 336, sc,
                                              SLOT_CLF);

  // patch embed -> Af -> quant into H
  k_patch<<<12800, 192, 0, stream>>>(x, PWQ, pb, sc, Af, sc + SLOT_EMB * 16);
  k_quant4<<<2048, 256, 0, stream>>>((const float4*)Af, (float4*)H, 19660800 / 4, sc, SLOT_EMB);

  for (int i = 0; i < NL; ++i) {
    int Lb = 16 + i * 16;
    // --- attention ---
    k_ln<true><<<(int)(ROWS / 4), 256, 0, stream>>>(H, ln1g + i * 192, ln1b + i * 192, nullptr,
                                                    XH, XL, (int)ROWS);
    {
      dim3 g(9, 800);
      k_gemm<0, false, 1><<<g, 256, 0, stream>>>(XH, XL, nullptr, 0, wqkv + (long)i * 110592,
                                                 Lb + 0, bqkv + i * 576, nullptr, nullptr, 576,
                                                 192, sc, Lb + 4, 192);
      k_gemm<0, false, 2><<<g, 256, 0, stream>>>(XH, XL, nullptr, 0, wqkv + (long)i * 110592,
                                                 Lb + 0, bqkv + i * 576, nullptr, U8, 576, 192,
                                                 sc, Lb + 4, 192);
    }
    {
      dim3 ga(7, 768);
      k_attn_s<0><<<ga, 256, 0, stream>>>(U8, GM, GL, sc, Lb + 4, Lb + 7, Lb + 8);
      k_attn_s<1><<<ga, 256, 0, stream>>>(U8, GM, GL, sc, Lb + 4, Lb + 7, Lb + 8);
      k_attn_pv<<<ga, 256, 0, stream>>>(U8, Af, GM, GL, sc, Lb + 4, Lb + 7, Lb + 8, Lb + 9);
    }
    // ctx fp32 (Af) -> int8 codes (U8)
    k_quant_codes<<<2048, 256, 0, stream>>>((const float4*)Af, (u32*)U8, 19660800 / 4, sc,
                                            Lb + 9);
    {
      dim3 g(3, 800);
      k_gemm<1, false, 0><<<g, 256, 0, stream>>>(nullptr, nullptr, U8, Lb + 9,
                                                 wo + (long)i * 36864, Lb + 1, bo + i * 192, Af,
                                                 nullptr, 192, 192, sc, Lb + 10, 192);
    }
    k_resadd4<<<2048, 256, 0, stream>>>((float4*)H, (const float4*)Af, 19660800 / 4, sc,
                                        Lb + 10);
    // --- MLP ---
    k_ln<true><<<(int)(ROWS / 4), 256, 0, stream>>>(H, ln2g + i * 192, ln2b + i * 192, nullptr,
                                                    XH, XL, (int)ROWS);
    {
      dim3 g(12, 800);
      k_gemm<0, true, 1><<<g, 256, 0, stream>>>(XH, XL, nullptr, 0, w1 + (long)i * 147456,
                                                Lb + 2, b1 + i * 768, nullptr, nullptr, 768, 192,
                                                sc, Lb + 11, 768);
      k_gemm<0, true, 2><<<g, 256, 0, stream>>>(XH, XL, nullptr, 0, w1 + (long)i * 147456,
                                                Lb + 2, b1 + i * 768, nullptr, U8, 768, 192, sc,
                                                Lb + 11, 768);
    }
    {
      dim3 g(3, 800);
      k_gemm<1, false, 0><<<g, 256, 0, stream>>>(nullptr, nullptr, U8, Lb + 11,
                                                 w2 + (long)i * 147456, Lb + 3, b2 + i * 192, Af,
                                                 nullptr, 192, 768, sc, Lb + 12, 192);
    }
    k_resadd4<<<2048, 256, 0, stream>>>((float4*)H, (const float4*)Af, 19660800 / 4, sc,
                                        Lb + 12);
  }

  // final LN + pool + classifier
  k_ln<false><<<(int)(ROWS / 4), 256, 0, stream>>>(H, lnfg, lnfb, Af, nullptr, nullptr,
                                                   (int)ROWS);
  k_pool<<<256, 192, 0, stream>>>(Af, POOL, sc + SLOT_POOL * 16);
  {
    dim3 g(7, 256);
    k_logits<<<g, 64, 0, stream>>>(POOL, CLFQ, clfb, sc, out);
  }
}